// Round 6
// baseline (859.914 us; speedup 1.0000x reference)
//
#include <hip/hip_runtime.h>

// WaveNet on gfx950, fp16 MFMA path, round 6.
// vs r5: layer kernel 5->3 barriers (separate Os buffer; gate+residual in regs;
// x^T written into dead Xs0), absolute fixed tiling (stable tile->XCD mapping
// across layers for L2 locality), head 13->7 barriers via double-buffered H1s.
// Stores stay fully coalesced (r3 lesson). 256-thread blocks, lb(256,3) so the
// VGPR cap (170) can never force accumulator spills (r4 lesson; check VGPR_Count).

#define TT 8192
#define HIDC 128
#define GOODC 2046
#define TGT 6146
#define NL 20

typedef _Float16 half8_t __attribute__((ext_vector_type(8)));
typedef _Float16 half4_t __attribute__((ext_vector_type(4)));
typedef float floatx4 __attribute__((ext_vector_type(4)));

__device__ __forceinline__ floatx4 mfma16(half8_t a, half8_t b, floatx4 c) {
  return __builtin_amdgcn_mfma_f32_16x16x32_f16(a, b, c, 0, 0, 0);
}

__device__ __forceinline__ float fast_sigmoid(float x) {
  return __builtin_amdgcn_rcpf(1.0f + __expf(-x));
}
__device__ __forceinline__ float fast_tanh(float x) {
  return 2.0f * __builtin_amdgcn_rcpf(1.0f + __expf(-2.0f * x)) - 1.0f;
}

// ---------------- weight prep: fp32 -> fp16, stacked layouts ----------------
__global__ void prep_kernel(const float* __restrict__ Wi, const float* __restrict__ Wf,
                            const float* __restrict__ Wg, const float* __restrict__ Wr,
                            const float* __restrict__ W1, const float* __restrict__ W2,
                            _Float16* __restrict__ WIh, _Float16* __restrict__ WFG,
                            _Float16* __restrict__ WRh, _Float16* __restrict__ W1h,
                            _Float16* __restrict__ W2h) {
  int idx = blockIdx.x * blockDim.x + threadIdx.x;
  int stride = gridDim.x * blockDim.x;
  // WFG[l][m][k]: m<128 -> Wf row m, else Wg row m-128; k<128 -> tap0 (u-d), else tap1 (u)
  for (int i = idx; i < NL * 256 * 256; i += stride) {
    int l = i >> 16; int m = (i >> 8) & 255; int k = i & 255;
    int tap = k >> 7; int ci = k & 127;
    float v;
    if (m < 128) v = Wf[(((size_t)l * 128 + m) * 128 + ci) * 2 + tap];
    else         v = Wg[(((size_t)l * 128 + (m - 128)) * 128 + ci) * 2 + tap];
    WFG[i] = (_Float16)v;
  }
  for (int i = idx; i < NL * 128 * 128; i += stride) WRh[i] = (_Float16)Wr[i];
  for (int i = idx; i < 128 * 256; i += stride) WIh[i] = (_Float16)Wi[i];
  for (int i = idx; i < 512 * 128; i += stride) W1h[i] = (_Float16)W1[i];
  for (int i = idx; i < 256 * 512; i += stride) W2h[i] = (_Float16)W2[i];
}

// ---------------- input 1x1 conv: R0[b][u][c] = Wi @ inputs + bi (fp16 out) ----------------
__global__ __launch_bounds__(256, 3) void input_kernel(
    const float* __restrict__ inp, const _Float16* __restrict__ WIh,
    const float* __restrict__ bi, _Float16* __restrict__ R0) {
  __shared__ __align__(16) _Float16 Xs[64][264];
  const int tid = threadIdx.x;
  const int lane = tid & 63;
  const int w = tid >> 6;
  const int ml = lane & 15;
  const int mq = lane >> 4;
  const int b = blockIdx.y;
  const int u0 = blockIdx.x * 64;
  const float* ib = inp + (size_t)b * 256 * TT;

  for (int i = tid; i < 64 * 16; i += 256) {
    int n4 = i & 15;
    int kg = i >> 4;
    const float* src = ib + (size_t)(kg * 4) * TT + u0 + n4 * 4;
    floatx4 c0 = *(const floatx4*)(src);
    floatx4 c1 = *(const floatx4*)(src + TT);
    floatx4 c2 = *(const floatx4*)(src + 2 * TT);
    floatx4 c3 = *(const floatx4*)(src + 3 * TT);
#pragma unroll
    for (int t = 0; t < 4; ++t) {
      half4_t h;
      h[0] = (_Float16)c0[t]; h[1] = (_Float16)c1[t];
      h[2] = (_Float16)c2[t]; h[3] = (_Float16)c3[t];
      *(half4_t*)&Xs[n4 * 4 + t][kg * 4] = h;
    }
  }
  __syncthreads();

  floatx4 acc[2][4];
#pragma unroll
  for (int a = 0; a < 2; ++a)
#pragma unroll
    for (int c = 0; c < 4; ++c) acc[a][c] = floatx4{0.f, 0.f, 0.f, 0.f};

  const _Float16* Aw = WIh + (size_t)(32 * w + ml) * 256;
  for (int kk = 0; kk < 8; ++kk) {
    const int ko = kk * 32 + mq * 8;
    half8_t a0 = *(const half8_t*)(Aw + ko);
    half8_t a1 = *(const half8_t*)(Aw + 16 * 256 + ko);
#pragma unroll
    for (int nt = 0; nt < 4; ++nt) {
      half8_t bv = *(const half8_t*)&Xs[nt * 16 + ml][ko];
      acc[0][nt] = mfma16(a0, bv, acc[0][nt]);
      acc[1][nt] = mfma16(a1, bv, acc[1][nt]);
    }
  }
  __syncthreads();
  float* Xf = (float*)&Xs[0][0];
#pragma unroll
  for (int mt = 0; mt < 2; ++mt) {
    const int mb = 32 * w + mt * 16 + mq * 4;
#pragma unroll
    for (int nt = 0; nt < 4; ++nt)
      *(floatx4*)&Xf[(nt * 16 + ml) * 132 + mb] = acc[mt][nt];
  }
  __syncthreads();
  _Float16* Rb = R0 + (size_t)b * TT * HIDC;
  for (int i = tid; i < 64 * 16; i += 256) {
    int n = i >> 4; int c = i & 15;
    floatx4 x0 = *(const floatx4*)&Xf[n * 132 + c * 8];
    floatx4 x1 = *(const floatx4*)&Xf[n * 132 + c * 8 + 4];
    floatx4 b0 = *(const floatx4*)(bi + c * 8);
    floatx4 b1v = *(const floatx4*)(bi + c * 8 + 4);
    half8_t h;
#pragma unroll
    for (int t = 0; t < 4; ++t) {
      h[t] = (_Float16)(x0[t] + b0[t]);
      h[4 + t] = (_Float16)(x1[t] + b1v[t]);
    }
    *(half8_t*)(Rb + (size_t)(u0 + n) * HIDC + c * 8) = h;
  }
}

// ---------------- one residual layer: 256 threads, N=64 absolute tile, 3 barriers ----------------
__global__ __launch_bounds__(256, 3) void layer_kernel(
    const _Float16* __restrict__ Rin, _Float16* __restrict__ Rout,
    const _Float16* __restrict__ WFG, const _Float16* __restrict__ WR,
    const float* __restrict__ bf, const float* __restrict__ bg,
    const float* __restrict__ br, int d, int ustart) {
  __shared__ __align__(16) _Float16 Xs0[64][136];  // tap0 (u-d); after b2 reused for R_new^T
  __shared__ __align__(16) _Float16 Xs1[64][136];  // tap1 (u) = R_old (stable all kernel)
  __shared__ __align__(16) _Float16 Os[64][136];   // gated out
  const int tid = threadIdx.x;
  const int lane = tid & 63;
  const int w = tid >> 6;   // 0..3 : m-group (32 f-rows + 32 g-rows)
  const int ml = lane & 15;
  const int mq = lane >> 4;
  const int b = blockIdx.y;
  const int u0 = blockIdx.x * 64;   // ABSOLUTE tiling: stable tile->XCD map across layers
  if (u0 + 63 < ustart) return;     // tile entirely below valid range
  const _Float16* Rb = Rin + (size_t)b * TT * HIDC;
  _Float16* Ro = Rout + (size_t)b * TT * HIDC;

  // ---- stage both taps (2048 x 16B chunks, 8 per thread), 1 barrier ----
#pragma unroll
  for (int it = 0; it < 8; ++it) {
    int j = it * 256 + tid;          // n(6b) | tap(1b) | c(4b)
    int c = j & 15;
    int tap = (j >> 4) & 1;
    int n = j >> 5;
    int u = u0 + n - (tap ? 0 : d);
    u = min(max(u, 0), TT - 1);      // clamp; garbage rows masked at store
    _Float16* dst = tap ? &Xs1[n][c * 8] : &Xs0[n][c * 8];
    *(half8_t*)dst = *(const half8_t*)(Rb + (size_t)u * HIDC + c * 8);
  }
  __syncthreads();  // b1

  // ---- GEMM1: [f;g](256 rows) x K=256; wave w owns f-rows & g-rows [32w,32w+32) ----
  floatx4 accF[2][4], accG[2][4];
#pragma unroll
  for (int a = 0; a < 2; ++a)
#pragma unroll
    for (int c = 0; c < 4; ++c) {
      accF[a][c] = floatx4{0.f, 0.f, 0.f, 0.f};
      accG[a][c] = floatx4{0.f, 0.f, 0.f, 0.f};
    }
  const _Float16* Af = WFG + (size_t)(32 * w + ml) * 256;
  const _Float16* Ag = Af + 128 * 256;
#pragma unroll
  for (int h = 0; h < 2; ++h) {
    const _Float16(*X)[136] = h ? Xs1 : Xs0;
#pragma unroll
    for (int kk = 0; kk < 4; ++kk) {
      const int ko = kk * 32 + mq * 8;   // [0,128) LDS col
      const int kw = h * 128 + ko;       // weight col
      half8_t aF0 = *(const half8_t*)(Af + kw);
      half8_t aF1 = *(const half8_t*)(Af + 16 * 256 + kw);
      half8_t aG0 = *(const half8_t*)(Ag + kw);
      half8_t aG1 = *(const half8_t*)(Ag + 16 * 256 + kw);
#pragma unroll
      for (int nt = 0; nt < 4; ++nt) {
        half8_t bv = *(const half8_t*)&X[nt * 16 + ml][ko];
        accF[0][nt] = mfma16(aF0, bv, accF[0][nt]);
        accF[1][nt] = mfma16(aF1, bv, accF[1][nt]);
        accG[0][nt] = mfma16(aG0, bv, accG[0][nt]);
        accG[1][nt] = mfma16(aG1, bv, accG[1][nt]);
      }
    }
  }

  // ---- gate in registers, write straight to Os (own cells, no conflict) ----
#pragma unroll
  for (int mt = 0; mt < 2; ++mt) {
    const int mb = 32 * w + mt * 16 + mq * 4;
    floatx4 bfv = *(const floatx4*)(bf + mb);
    floatx4 bgv = *(const floatx4*)(bg + mb);
#pragma unroll
    for (int nt = 0; nt < 4; ++nt) {
      half4_t o;
#pragma unroll
      for (int r = 0; r < 4; ++r) {
        float fv = fast_tanh(accF[mt][nt][r] + bfv[r]);
        float gv = fast_sigmoid(accG[mt][nt][r] + bgv[r]);
        o[r] = (_Float16)(fv * gv);
      }
      *(half4_t*)&Os[nt * 16 + ml][mb] = o;
    }
  }
  __syncthreads();  // b2: Os visible; also all Xs0 reads complete

  // ---- GEMM2: x = WR(128x128) @ out ----
  floatx4 accX[2][4];
#pragma unroll
  for (int a = 0; a < 2; ++a)
#pragma unroll
    for (int c = 0; c < 4; ++c) accX[a][c] = floatx4{0.f, 0.f, 0.f, 0.f};
  const _Float16* Ar = WR + (size_t)(32 * w + ml) * 128;
#pragma unroll
  for (int kk = 0; kk < 4; ++kk) {
    const int ko = kk * 32 + mq * 8;
    half8_t a0 = *(const half8_t*)(Ar + ko);
    half8_t a1 = *(const half8_t*)(Ar + 16 * 128 + ko);
#pragma unroll
    for (int nt = 0; nt < 4; ++nt) {
      half8_t bv = *(const half8_t*)&Os[nt * 16 + ml][ko];
      accX[0][nt] = mfma16(a0, bv, accX[0][nt]);
      accX[1][nt] = mfma16(a1, bv, accX[1][nt]);
    }
  }

  // ---- residual in registers (R_old from Xs1), write R_new^T into dead Xs0 ----
#pragma unroll
  for (int mt = 0; mt < 2; ++mt) {
    const int mb = 32 * w + mt * 16 + mq * 4;
    floatx4 brv = *(const floatx4*)(br + mb);
#pragma unroll
    for (int nt = 0; nt < 4; ++nt) {
      const int n = nt * 16 + ml;
      half4_t rold = *(const half4_t*)&Xs1[n][mb];
      half4_t o;
#pragma unroll
      for (int r = 0; r < 4; ++r)
        o[r] = (_Float16)(accX[mt][nt][r] + brv[r] + (float)rold[r]);
      *(half4_t*)&Xs0[n][mb] = o;   // Xs0 dead since b2 (GEMM1 reads done)
    }
  }
  __syncthreads();  // b3

  // ---- coalesced store: 16B/lane, row-contiguous, masked to valid range ----
#pragma unroll
  for (int it = 0; it < 4; ++it) {
    int j = it * 256 + tid;
    int n = j >> 4, c = j & 15;
    int u = u0 + n;
    if (u >= ustart)
      *(half8_t*)(Ro + (size_t)u * HIDC + c * 8) = *(const half8_t*)&Xs0[n][c * 8];
  }
}

// ---------------- head: 256 threads, N=64, 4 mid-passes, double-buffered H1s ----------------
__global__ __launch_bounds__(256, 3) void head_kernel(
    const _Float16* __restrict__ Rfin, const _Float16* __restrict__ R0,
    const _Float16* __restrict__ W1h, const _Float16* __restrict__ W2h,
    const float* __restrict__ b1, const float* __restrict__ b2,
    float* __restrict__ out) {
  __shared__ __align__(16) _Float16 Hs[64][136];      // relu(final) [n][c=128]
  __shared__ __align__(16) _Float16 H1s[2][64][136];  // mid chunk, double-buffered
  const int tid = threadIdx.x;
  const int lane = tid & 63;
  const int w = tid >> 6;   // 0..3
  const int ml = lane & 15;
  const int mq = lane >> 4;
  const int b = blockIdx.y;
  const int u0 = GOODC + blockIdx.x * 64;
  const _Float16* Ra = Rfin + (size_t)b * TT * HIDC;
  const _Float16* Rz = R0 + (size_t)b * TT * HIDC;

  // stage relu(Rfin - R0)
#pragma unroll
  for (int it = 0; it < 4; ++it) {
    int j = it * 256 + tid;
    int n = j >> 4; int c = j & 15;
    int u = min(u0 + n, TT - 1);
    half8_t a = *(const half8_t*)(Ra + (size_t)u * HIDC + c * 8);
    half8_t z = *(const half8_t*)(Rz + (size_t)u * HIDC + c * 8);
    half8_t h;
#pragma unroll
    for (int t = 0; t < 8; ++t) {
      float v = (float)a[t] - (float)z[t];
      h[t] = (_Float16)(v > 0.f ? v : 0.f);
    }
    *(half8_t*)&Hs[n][c * 8] = h;
  }
  __syncthreads();

  floatx4 accO[4][4];  // wave w out-rows [64w,64w+64): m = 64w+16mt+4mq+r, n = 16nt+ml
#pragma unroll
  for (int a = 0; a < 4; ++a)
#pragma unroll
    for (int c = 0; c < 4; ++c) accO[a][c] = floatx4{0.f, 0.f, 0.f, 0.f};

  for (int p = 0; p < 4; ++p) {
    // GEMM1: mid rows [128p,128p+128); wave w owns 32 rows
    floatx4 acc1[2][4];
#pragma unroll
    for (int a = 0; a < 2; ++a)
#pragma unroll
      for (int c = 0; c < 4; ++c) acc1[a][c] = floatx4{0.f, 0.f, 0.f, 0.f};
    const _Float16* A1 = W1h + (size_t)(128 * p + 32 * w + ml) * 128;
#pragma unroll
    for (int kk = 0; kk < 4; ++kk) {
      const int ko = kk * 32 + mq * 8;
      half8_t av0 = *(const half8_t*)(A1 + ko);
      half8_t av1 = *(const half8_t*)(A1 + 16 * 128 + ko);
#pragma unroll
      for (int nt = 0; nt < 4; ++nt) {
        half8_t bv = *(const half8_t*)&Hs[nt * 16 + ml][ko];
        acc1[0][nt] = mfma16(av0, bv, acc1[0][nt]);
        acc1[1][nt] = mfma16(av1, bv, acc1[1][nt]);
      }
    }
    // write relu(mid) into H1s[p&1] -- other buffer is the one GEMM2_{p-1} reads
#pragma unroll
    for (int mt = 0; mt < 2; ++mt) {
      const int kc = 32 * w + mt * 16 + mq * 4;
      floatx4 bv = *(const floatx4*)(b1 + 128 * p + kc);
#pragma unroll
      for (int nt = 0; nt < 4; ++nt) {
        half4_t h;
#pragma unroll
        for (int r = 0; r < 4; ++r) {
          float v = acc1[mt][nt][r] + bv[r];
          h[r] = (_Float16)(v > 0.f ? v : 0.f);
        }
        *(half4_t*)&H1s[p & 1][nt * 16 + ml][kc] = h;
      }
    }
    __syncthreads();  // one barrier per pass
    // GEMM2 accumulate: K = this 128-chunk
    const _Float16* A2 = W2h + (size_t)(64 * w + ml) * 512 + p * 128;
#pragma unroll
    for (int kk = 0; kk < 4; ++kk) {
      const int ko = kk * 32 + mq * 8;
#pragma unroll
      for (int nt = 0; nt < 4; ++nt) {
        half8_t bv = *(const half8_t*)&H1s[p & 1][(nt * 16 + ml)][ko];
#pragma unroll
        for (int mt = 0; mt < 4; ++mt) {
          half8_t av = *(const half8_t*)(A2 + (size_t)(mt * 16) * 512 + ko);
          accO[mt][nt] = mfma16(av, bv, accO[mt][nt]);
        }
      }
    }
  }
  __syncthreads();  // all GEMM2_3 reads + Hs reads complete

  // out^T through LDS (H1s area dead): [64 n][264 halfs], cols = 256 out ch
  _Float16* Ot = &H1s[0][0][0];
#pragma unroll
  for (int mt = 0; mt < 4; ++mt) {
    const int m = 64 * w + mt * 16 + mq * 4;
    floatx4 bv = *(const floatx4*)(b2 + m);
#pragma unroll
    for (int nt = 0; nt < 4; ++nt) {
      const int n = nt * 16 + ml;
      half4_t h;
#pragma unroll
      for (int r = 0; r < 4; ++r) h[r] = (_Float16)(accO[mt][nt][r] + bv[r]);
      *(half4_t*)&Ot[n * 264 + m] = h;
    }
  }
  __syncthreads();
  // coalesced fp32 stores: 2048 chunks of 8 ch, 8 per thread
#pragma unroll
  for (int it = 0; it < 8; ++it) {
    int j = it * 256 + tid;
    int n = j >> 5; int g = j & 31;
    int u = u0 + n;
    if (u < TT) {
      half8_t v = *(const half8_t*)&Ot[n * 264 + g * 8];
      float* dst = out + ((size_t)b * TGT + (u - GOODC)) * 256 + g * 8;
      floatx4 v0, v1;
#pragma unroll
      for (int t = 0; t < 4; ++t) { v0[t] = (float)v[t]; v1[t] = (float)v[4 + t]; }
      *(floatx4*)dst = v0;
      *(floatx4*)(dst + 4) = v1;
    }
  }
}

extern "C" void kernel_launch(void* const* d_in, const int* in_sizes, int n_in,
                              void* d_out, int out_size, void* d_ws, size_t ws_size,
                              hipStream_t stream) {
  const float* inputs = (const float*)d_in[0];
  const float* Wi = (const float*)d_in[1];
  const float* bi = (const float*)d_in[2];
  const float* Wf = (const float*)d_in[3];
  const float* bf = (const float*)d_in[4];
  const float* Wg = (const float*)d_in[5];
  const float* bg = (const float*)d_in[6];
  const float* Wr = (const float*)d_in[7];
  const float* br = (const float*)d_in[8];
  const float* W1 = (const float*)d_in[9];
  const float* b1 = (const float*)d_in[10];
  const float* W2 = (const float*)d_in[11];
  const float* b2 = (const float*)d_in[12];
  float* out = (float*)d_out;

  // workspace layout (~54 MB): three fp16 res buffers + fp16 weights
  char* ws = (char*)d_ws;
  _Float16* R0h = (_Float16*)(ws + 0);
  _Float16* Ph  = (_Float16*)(ws + 16777216);
  _Float16* Qh  = (_Float16*)(ws + 33554432);
  _Float16* WFG = (_Float16*)(ws + 50331648);
  _Float16* WRh = (_Float16*)(ws + 52953088);
  _Float16* WIh = (_Float16*)(ws + 53608448);
  _Float16* W1h = (_Float16*)(ws + 53673984);
  _Float16* W2h = (_Float16*)(ws + 53805056);

  prep_kernel<<<dim3(512), dim3(256), 0, stream>>>(Wi, Wf, Wg, Wr, W1, W2,
                                                   WIh, WFG, WRh, W1h, W2h);
  input_kernel<<<dim3(TT / 64, 8), dim3(256), 0, stream>>>(inputs, WIh, bi, R0h);

  int S = 0;
  for (int l = 0; l < NL; ++l) {
    int d = 1 << (l % 10);
    int ustart = S + d;
    const _Float16* rin = (l == 0) ? R0h : ((l & 1) ? Ph : Qh);
    _Float16* rout = (l & 1) ? Qh : Ph;
    // absolute fixed grid: stable tile->XCD mapping across layers
    layer_kernel<<<dim3(TT / 64, 8), dim3(256), 0, stream>>>(
        rin, rout, WFG + (size_t)l * 65536, WRh + (size_t)l * 16384,
        bf + l * 128, bg + l * 128, br + l * 128, d, ustart);
    S = ustart;
  }
  // after l=19 (odd), final res is in Qh
  head_kernel<<<dim3((TGT + 63) / 64, 8), dim3(256), 0, stream>>>(
      Qh, R0h, W1h, W2h, b1, b2, out);
}